// Round 8
// baseline (1352.763 us; speedup 1.0000x reference)
//
#include <hip/hip_runtime.h>
#include <hip/hip_bf16.h>
#include <cstdint>

#define T_TOK 32768
#define HD 512
#define ID 2048
#define NE 8
#define ROWS_PAD_MAX 66560  // 520*128 >= 2*T_TOK + NE*127
#define NMB 520             // ROWS_PAD_MAX/128
#define HPAD 136            // h-chunk LDS row pitch (ushort): 272B = 17*16B, breaks bank alignment

typedef __bf16 bf16x8 __attribute__((ext_vector_type(8)));
typedef float f32x4 __attribute__((ext_vector_type(4)));

__device__ __forceinline__ ushort f2bf(float f) {
  __hip_bfloat16 h = __float2bfloat16(f);
  return *reinterpret_cast<ushort*>(&h);
}

__device__ __forceinline__ void gload16(const ushort* g, ushort* l) {
  __builtin_amdgcn_global_load_lds((__attribute__((address_space(1))) void*)(void*)g,
                                   (__attribute__((address_space(3))) void*)(void*)l,
                                   16, 0, 0);
}

// ---------------- zero out + routing counters ----------------
__global__ void k_zero(float4* out4, int n4, int* counts) {
  if (blockIdx.x == 0 && threadIdx.x < NE) counts[threadIdx.x] = 0;
  float4 z = make_float4(0.f, 0.f, 0.f, 0.f);
  for (int i = blockIdx.x * blockDim.x + threadIdx.x; i < n4; i += gridDim.x * blockDim.x)
    out4[i] = z;
}

// ---------------- transpose+cast weights: in [z][R][C] f32 -> out [z][C][R] bf16 ----------------
__global__ void k_transpose(const float* __restrict__ in, ushort* __restrict__ out, int R, int C) {
  __shared__ float tile[32][33];
  int z = blockIdx.z;
  const float* src = in + (size_t)z * R * C;
  ushort* dst = out + (size_t)z * R * C;
  int c0 = blockIdx.x * 32, r0 = blockIdx.y * 32;
  int tx = threadIdx.x, ty = threadIdx.y;  // (32,8)
#pragma unroll
  for (int i = 0; i < 32; i += 8)
    tile[ty + i][tx] = src[(size_t)(r0 + ty + i) * C + c0 + tx];
  __syncthreads();
#pragma unroll
  for (int i = 0; i < 32; i += 8)
    dst[(size_t)(c0 + ty + i) * R + r0 + tx] = f2bf(tile[tx][ty + i]);
}

// ---------------- fused cast x->bf16 + gate top-2 (NO atomics) ----------------
__global__ __launch_bounds__(256) void k_cast_gate(const float* __restrict__ x,
                                                   const float* __restrict__ gw,
                                                   const float* __restrict__ gb,
                                                   ushort* __restrict__ xb,
                                                   uchar2* __restrict__ tope,
                                                   float2* __restrict__ tw) {
  int t = blockIdx.x * 4 + (threadIdx.x >> 6);
  int lane = threadIdx.x & 63;
  const float4* xr = (const float4*)(x + (size_t)t * HD);
  float4 v0 = xr[lane];
  float4 v1 = xr[lane + 64];
  ushort4 o0, o1;
  o0.x = f2bf(v0.x); o0.y = f2bf(v0.y); o0.z = f2bf(v0.z); o0.w = f2bf(v0.w);
  o1.x = f2bf(v1.x); o1.y = f2bf(v1.y); o1.z = f2bf(v1.z); o1.w = f2bf(v1.w);
  ushort4* xw = (ushort4*)(xb + (size_t)t * HD);
  xw[lane] = o0;
  xw[lane + 64] = o1;
  float xv[8] = {v0.x, v0.y, v0.z, v0.w, v1.x, v1.y, v1.z, v1.w};
  float p[8] = {0, 0, 0, 0, 0, 0, 0, 0};
  const float* g0 = gw + (size_t)lane * 4 * 8;
  const float* g1 = gw + (size_t)(256 + lane * 4) * 8;
#pragma unroll
  for (int j = 0; j < 4; ++j)
#pragma unroll
    for (int e = 0; e < 8; ++e) p[e] += xv[j] * g0[j * 8 + e];
#pragma unroll
  for (int j = 0; j < 4; ++j)
#pragma unroll
    for (int e = 0; e < 8; ++e) p[e] += xv[4 + j] * g1[j * 8 + e];
#pragma unroll
  for (int e = 0; e < 8; ++e) {
    float s = p[e];
    for (int off = 32; off; off >>= 1) s += __shfl_xor(s, off);
    p[e] = s + gb[e];
  }
  float mx = p[0];
#pragma unroll
  for (int e = 1; e < 8; ++e) mx = fmaxf(mx, p[e]);
  float Z = 0.f;
  float pr[8];
#pragma unroll
  for (int e = 0; e < 8; ++e) { pr[e] = expf(p[e] - mx); Z += pr[e]; }
  float invZ = 1.f / Z;
#pragma unroll
  for (int e = 0; e < 8; ++e) pr[e] *= invZ;
  float v1v = pr[0]; int i1 = 0;
#pragma unroll
  for (int e = 1; e < 8; ++e) { if (pr[e] > v1v) { v1v = pr[e]; i1 = e; } }
  float v2v = -1.f; int i2 = 0;
#pragma unroll
  for (int e = 0; e < 8; ++e) { if (e != i1 && pr[e] > v2v) { v2v = pr[e]; i2 = e; } }
  float c1 = 1.f / (1.f + expf(v2v - v1v));
  float c2 = 1.f - c1;
  if (lane == 0) {
    tope[t] = make_uchar2((unsigned char)i1, (unsigned char)i2);
    tw[t] = make_float2(c1, c2);
  }
}

// ---------------- route: wave-aggregated compaction ----------------
__global__ __launch_bounds__(256) void k_route(const uchar2* __restrict__ tope,
                                               const float2* __restrict__ tw,
                                               int* __restrict__ rtok, float* __restrict__ rw,
                                               int* __restrict__ counts) {
  int t = blockIdx.x * 256 + threadIdx.x;
  int lane = threadIdx.x & 63;
  uchar2 ei = tope[t];
  float2 c = tw[t];
  unsigned long long below = (1ull << lane) - 1ull;
#pragma unroll
  for (int e = 0; e < NE; ++e) {
    bool sel = (ei.x == e) || (ei.y == e);
    unsigned long long mask = __ballot(sel);
    if (mask == 0ull) continue;
    int cnt = __popcll(mask);
    int base = 0;
    if (lane == 0) base = atomicAdd(&counts[e], cnt);
    base = __shfl(base, 0);
    if (sel) {
      int pos = base + __popcll(mask & below);
      rtok[e * T_TOK + pos] = t;
      rw[e * T_TOK + pos] = (ei.x == e) ? c.x : c.y;
    }
  }
}

// ---------------- 128-aligned exclusive prefix of counts ----------------
__global__ void k_offsets(const int* __restrict__ counts, int* __restrict__ poff) {
  if (threadIdx.x == 0) {
    int acc = 0;
    poff[0] = 0;
#pragma unroll
    for (int e = 0; e < NE; ++e) {
      acc += ((counts[e] + 127) >> 7) << 7;
      poff[e + 1] = acc;
    }
  }
}

__device__ __forceinline__ int find_expert(const int* poff, int v) {
  int e = 0;
#pragma unroll
  for (int j = 1; j < NE; ++j) e += (v >= poff[j]) ? 1 : 0;
  return e;
}

// ---------------- FUSED FFN: out[tok] += coef*(relu(X@w1^T+b1)@w2^T + b2) ----------------
// One block = 128 routed tokens, full ID in 16 chunks of 128; h-chunk lives in LDS only.
__global__ __launch_bounds__(512, 2) void k_ffn(const ushort* __restrict__ xb,
                                                const ushort* __restrict__ w1t,
                                                const ushort* __restrict__ w2t,
                                                const float* __restrict__ b1,
                                                const float* __restrict__ b2,
                                                const int* __restrict__ rtok,
                                                const float* __restrict__ rw,
                                                const int* __restrict__ counts,
                                                const int* __restrict__ poff,
                                                float* __restrict__ out) {
  // XCD-chunked bijective swizzle: 520 = 8 * 65
  int bid = blockIdx.x;
  int mb = (bid & 7) * (NMB / 8) + (bid >> 3);
  int v = mb << 7;
  if (v >= poff[NE]) return;
  int e = find_expert(poff, v);
  int cnt = counts[e];
  int m0 = v - poff[e];

  __shared__ __attribute__((aligned(16))) ushort Xs[128 * 32];   // 8 KB  X k1-strip
  __shared__ __attribute__((aligned(16))) ushort Ws[128 * 32];   // 8 KB  w1t strip
  __shared__ __attribute__((aligned(16))) ushort Hs[128 * HPAD]; // 34 KB h chunk (padded)
  __shared__ int stok[128];
  __shared__ float scoef[128];

  int tid = threadIdx.x, lane = tid & 63, wv = tid >> 6;  // 8 waves
  int lr = lane & 15, lk = lane >> 4;
  int wr = wv >> 2, wc = wv & 3;  // 2 x 4 wave grid

  if (tid < 128) {
    int idx = min(m0 + tid, cnt - 1);
    stok[tid] = rtok[e * T_TOK + idx];
    scoef[tid] = rw[e * T_TOK + idx];
  }
  __syncthreads();

  // staging: thread t stages 16B chunk t of Xs AND of Ws (512 chunks each)
  int srow = tid >> 2;            // 0..127
  int skq = (tid & 3) * 8;        // k1 elem offset
  const ushort* aBase = xb + (size_t)stok[srow] * HD + skq;
  const ushort* bBase0 = w1t + ((size_t)e * ID + srow) * HD + skq;
  ushort* XsW = Xs + wv * 512;    // wave-uniform LDS dst (1 KB/wave)
  ushort* WsW = Ws + wv * 512;

  // w2t B-frag bases (global->reg): n fixed per lane per ni
  const ushort* w2b = w2t + ((size_t)e * HD + wc * 128 + lr) * ID + lk * 8;

  f32x4 acc2[4][8] = {};  // out tile: wave = 64 rows x 128 cols

#pragma unroll 1
  for (int cc = 0; cc < ID / 128; ++cc) {
    const ushort* bBase = bBase0 + (size_t)cc * 128 * HD;
    // b1 bias for this chunk (2 cols per lane)
    float b1c0 = b1[e * ID + cc * 128 + wc * 32 + lr];
    float b1c1 = b1[e * ID + cc * 128 + wc * 32 + 16 + lr];

    // ---- GEMM1: h_c = X[128x512] @ w1t_chunk^T -> acc1 ----
    f32x4 acc1[4][2] = {};
    for (int k0 = 0; k0 < HD; k0 += 32) {
      gload16(aBase + k0, XsW);
      gload16(bBase + k0, WsW);
      __syncthreads();
      bf16x8 af[4], bfr[2];
#pragma unroll
      for (int i = 0; i < 4; ++i)
        af[i] = *(const bf16x8*)(Xs + (wr * 64 + i * 16 + lr) * 32 + lk * 8);
#pragma unroll
      for (int i = 0; i < 2; ++i)
        bfr[i] = *(const bf16x8*)(Ws + (wc * 32 + i * 16 + lr) * 32 + lk * 8);
#pragma unroll
      for (int mi = 0; mi < 4; ++mi)
#pragma unroll
        for (int ni = 0; ni < 2; ++ni)
          acc1[mi][ni] = __builtin_amdgcn_mfma_f32_16x16x32_bf16(af[mi], bfr[ni], acc1[mi][ni], 0, 0, 0);
      __syncthreads();
    }

    // ---- relu+b1, write h chunk to LDS ----
#pragma unroll
    for (int mi = 0; mi < 4; ++mi) {
#pragma unroll
      for (int ni = 0; ni < 2; ++ni) {
        int icol = wc * 32 + ni * 16 + lr;
        float bv = ni ? b1c1 : b1c0;
#pragma unroll
        for (int r = 0; r < 4; ++r) {
          int m = wr * 64 + mi * 16 + lk * 4 + r;
          Hs[m * HPAD + icol] = f2bf(fmaxf(acc1[mi][ni][r] + bv, 0.f));
        }
      }
    }
    __syncthreads();

    // ---- GEMM2: acc2 += h_c[128x128] @ w2t_chunk^T (B from global, L2-hot) ----
#pragma unroll
    for (int ks = 0; ks < 4; ++ks) {
      bf16x8 a2[4];
#pragma unroll
      for (int mi = 0; mi < 4; ++mi)
        a2[mi] = *(const bf16x8*)(Hs + (wr * 64 + mi * 16 + lr) * HPAD + ks * 32 + lk * 8);
#pragma unroll
      for (int ni = 0; ni < 8; ++ni) {
        bf16x8 b2f = *(const bf16x8*)(w2b + (size_t)ni * 16 * ID + cc * 128 + ks * 32);
#pragma unroll
        for (int mi = 0; mi < 4; ++mi)
          acc2[mi][ni] = __builtin_amdgcn_mfma_f32_16x16x32_bf16(a2[mi], b2f, acc2[mi][ni], 0, 0, 0);
      }
    }
    __syncthreads();  // protect Hs (and Xs/Ws) before next chunk overwrites
  }

  // ---- epilogue: out[tok] += coef * (acc2 + b2), atomic f32 ----
#pragma unroll
  for (int ni = 0; ni < 8; ++ni) {
    int n = wc * 128 + ni * 16 + lr;
    float b2v = b2[e * HD + n];
#pragma unroll
    for (int mi = 0; mi < 4; ++mi) {
#pragma unroll
      for (int r = 0; r < 4; ++r) {
        int m = wr * 64 + mi * 16 + lk * 4 + r;
        if (m0 + m < cnt) {
          float vv = (acc2[mi][ni][r] + b2v) * scoef[m];
          unsafeAtomicAdd(&out[(size_t)stok[m] * HD + n], vv);
        }
      }
    }
  }
}

// ---------------- host ----------------
extern "C" void kernel_launch(void* const* d_in, const int* in_sizes, int n_in,
                              void* d_out, int out_size, void* d_ws, size_t ws_size,
                              hipStream_t stream) {
  const float* x  = (const float*)d_in[0];
  const float* gw = (const float*)d_in[1];
  const float* gb = (const float*)d_in[2];
  const float* w1 = (const float*)d_in[3];
  const float* b1 = (const float*)d_in[4];
  const float* w2 = (const float*)d_in[5];
  const float* b2 = (const float*)d_in[6];
  float* out = (float*)d_out;

  char* p = (char*)d_ws;
  ushort* xb   = (ushort*)p; p += (size_t)T_TOK * HD * 2;   // 33.5 MB
  ushort* w1t  = (ushort*)p; p += (size_t)NE * ID * HD * 2; // 16.8 MB
  ushort* w2t  = (ushort*)p; p += (size_t)NE * HD * ID * 2; // 16.8 MB
  int*    rtok = (int*)p;    p += (size_t)NE * T_TOK * 4;   // 1 MB
  float*  rw   = (float*)p;  p += (size_t)NE * T_TOK * 4;   // 1 MB
  uchar2* tope = (uchar2*)p; p += (size_t)T_TOK * 2;
  float2* tw   = (float2*)p; p += (size_t)T_TOK * 8;
  int*  counts = (int*)p;                                   // counts[8]
  int*  poff   = counts + 16;                               // poff[9]
  p += 128;

  k_zero<<<2048, 256, 0, stream>>>((float4*)out, T_TOK * HD / 4, counts);
  k_cast_gate<<<T_TOK / 4, 256, 0, stream>>>(x, gw, gb, xb, tope, tw);
  k_route<<<T_TOK / 256, 256, 0, stream>>>(tope, tw, rtok, rw, counts);
  k_offsets<<<1, 64, 0, stream>>>(counts, poff);
  // w1: [E][512][2048] -> w1t [E][2048][512]
  k_transpose<<<dim3(ID / 32, HD / 32, NE), dim3(32, 8), 0, stream>>>(w1, w1t, HD, ID);
  // w2: [E][2048][512] -> w2t [E][512][2048]
  k_transpose<<<dim3(HD / 32, ID / 32, NE), dim3(32, 8), 0, stream>>>(w2, w2t, ID, HD);

  k_ffn<<<NMB, 512, 0, stream>>>(xb, w1t, w2t, b1, b2, rtok, rw, counts, poff, out);
}